// Round 6
// baseline (202.689 us; speedup 1.0000x reference)
//
#include <hip/hip_runtime.h>
#include <hip/hip_cooperative_groups.h>
#include <math.h>

namespace cg = cooperative_groups;

#define QN 128
#define SN 512
#define DN 768
#define TDN 1536
#define CN 64
#define KSPLIT 4
#define KCH 192   // 768 / KSPLIT

#define HQP_ELEMS (KSPLIT * QN * TDN)
#define HSP_ELEMS (KSPLIT * SN * TDN)

typedef short short8 __attribute__((ext_vector_type(8)));
typedef float f32x4 __attribute__((ext_vector_type(4)));

#define LDS_STRIDE 40            // 32 k + 8 pad (bf16 units) -> 2-way bank alias only
#define PLANE (128 * LDS_STRIDE) // shorts per plane

__device__ __forceinline__ short bf16_rtn(float x) {
    unsigned u = __float_as_uint(x);
    return (short)((u + 0x7fffu + ((u >> 16) & 1u)) >> 16);
}
__device__ __forceinline__ float bf16_tof(short s) {
    return __uint_as_float(((unsigned)(unsigned short)s) << 16);
}

// ---------------------------------------------------------------------------
// Single cooperative kernel, grid 256 x 256 (1 block/CU), 3 phases:
//  P1 (bid<240): bf16x3 MFMA GEMM, split-K 4 -> hqp/hsp partials.
//      bid>=240: zero aggbuf.
//  P2 (all 256): score + run-length label reduce -> atomicAdd aggbuf[q][c].
//  P3 (bid==0): thread-per-query softmax/argmax/loss -> out.
// Phases separated by cg::this_grid().sync() (device-scope fence included).
// LDS: union of gemm planes (80 KiB) and score/finale buffers (66 KiB).
// ---------------------------------------------------------------------------
__global__ __launch_bounds__(256) void mega_kernel(
    const float* __restrict__ query, const float* __restrict__ support,
    const float* __restrict__ W1, const float* __restrict__ b1,
    const float* __restrict__ W2, const int* __restrict__ labels,
    const int* __restrict__ tgt, float* __restrict__ hqp,
    float* __restrict__ hsp, float* __restrict__ aggbuf,
    float* __restrict__ out)
{
    const int bid = blockIdx.x;
    const int tid = threadIdx.x;

    __shared__ union {
        short g[2][4][PLANE];                 // gemm: [buf][Ah,Al,Bh,Bl]
        struct {
            float hqT[96][64];
            float hsT[96][64];
            float w2s[96];
            float sc[64][68];
            int   lab[64];
            float cnt[64];
            float red[4];
        } s;
    } sh;

    cg::grid_group grid = cg::this_grid();

    // ================= Phase 1: GEMM (bid<240) / zero aggbuf (bid>=240) ====
    if (bid >= 240) {
        if (bid == 240) {    // zero aggbuf: 256 thr x 32 floats = 8192
            #pragma unroll
            for (int i = 0; i < 8; ++i)
                *(float4*)&aggbuf[(tid * 8 + i * 2048)] = make_float4(0.f,0.f,0.f,0.f);
        }
    } else {
        const int nt = bid % 12;         // n-tile 0..11
        const int mt = (bid / 12) % 5;   // 0=hq, 1..4=hs row-tiles
        const int kz = bid / 60;         // split-K 0..3

        const float* A;
        float* Cout;
        int M0, Koff;
        if (mt == 0) { A = query;   M0 = 0;              Koff = 0;  Cout = hqp + (size_t)kz * QN * TDN; }
        else         { A = support; M0 = (mt - 1) * 128; Koff = DN; Cout = hsp + (size_t)kz * SN * TDN; }

        const int r  = tid >> 1;         // staging row 0..127
        const int kh = (tid & 1) * 16;   // k-offset 0 or 16

        const float* Arow = &A [(size_t)(M0 + r) * DN  + kz * KCH + kh];
        const float* Brow = &W1[(size_t)(nt * 128 + r) * TDN + Koff + kz * KCH + kh];

        f32x4 acc[4][4];
        #pragma unroll
        for (int i = 0; i < 4; ++i)
            #pragma unroll
            for (int j = 0; j < 4; ++j)
                acc[i][j] = (f32x4){0.f, 0.f, 0.f, 0.f};

        auto stage = [&](short* plane, float4 v0, float4 v1, float4 v2, float4 v3) {
            float f[16] = {v0.x,v0.y,v0.z,v0.w, v1.x,v1.y,v1.z,v1.w,
                           v2.x,v2.y,v2.z,v2.w, v3.x,v3.y,v3.z,v3.w};
            short hi[16], lo[16];
            #pragma unroll
            for (int i = 0; i < 16; ++i) {
                hi[i] = bf16_rtn(f[i]);
                lo[i] = bf16_rtn(f[i] - bf16_tof(hi[i]));
            }
            short* dsth = plane + r * LDS_STRIDE + kh;
            #pragma unroll
            for (int i = 0; i < 16; ++i) dsth[i] = hi[i];
            short* dstl = plane + PLANE + r * LDS_STRIDE + kh;
            #pragma unroll
            for (int i = 0; i < 16; ++i) dstl[i] = lo[i];
        };

        {   // prologue: stage step 0 into buf 0
            float4 a0 = *(const float4*)(Arow),     a1 = *(const float4*)(Arow + 4);
            float4 a2 = *(const float4*)(Arow + 8), a3 = *(const float4*)(Arow + 12);
            float4 b0 = *(const float4*)(Brow),     b1 = *(const float4*)(Brow + 4);
            float4 b2 = *(const float4*)(Brow + 8), b3 = *(const float4*)(Brow + 12);
            stage(sh.g[0][0], a0, a1, a2, a3);
            stage(sh.g[0][2], b0, b1, b2, b3);
        }
        __syncthreads();

        const int lane  = tid & 63;
        const int w     = tid >> 6;
        const int lm    = lane & 15;
        const int quad  = lane >> 4;
        const int wrow0 = (w >> 1) * 64;
        const int wcol0 = (w & 1) * 64;

        int buf = 0;
        for (int step = 0; step < 6; ++step) {
            float4 a0, a1, a2, a3, b0, b1, b2, b3;
            if (step < 5) {
                const float* An = Arow + (step + 1) * 32;
                const float* Bn = Brow + (step + 1) * 32;
                a0 = *(const float4*)(An);     a1 = *(const float4*)(An + 4);
                a2 = *(const float4*)(An + 8); a3 = *(const float4*)(An + 12);
                b0 = *(const float4*)(Bn);     b1 = *(const float4*)(Bn + 4);
                b2 = *(const float4*)(Bn + 8); b3 = *(const float4*)(Bn + 12);
            }

            const short* Ah = sh.g[buf][0];
            const short* Al = sh.g[buf][1];
            const short* Bh = sh.g[buf][2];
            const short* Bl = sh.g[buf][3];

            short8 ah[4], al[4], bh[4], bl[4];
            #pragma unroll
            for (int mi = 0; mi < 4; ++mi) {
                int off = (wrow0 + mi * 16 + lm) * LDS_STRIDE + quad * 8;
                ah[mi] = *(const short8*)&Ah[off];
                al[mi] = *(const short8*)&Al[off];
            }
            #pragma unroll
            for (int ni = 0; ni < 4; ++ni) {
                int off = (wcol0 + ni * 16 + lm) * LDS_STRIDE + quad * 8;
                bh[ni] = *(const short8*)&Bh[off];
                bl[ni] = *(const short8*)&Bl[off];
            }
            #pragma unroll
            for (int mi = 0; mi < 4; ++mi)
                #pragma unroll
                for (int ni = 0; ni < 4; ++ni) {
                    acc[mi][ni] = __builtin_amdgcn_mfma_f32_16x16x32_bf16(ah[mi], bh[ni], acc[mi][ni], 0, 0, 0);
                    acc[mi][ni] = __builtin_amdgcn_mfma_f32_16x16x32_bf16(ah[mi], bl[ni], acc[mi][ni], 0, 0, 0);
                    acc[mi][ni] = __builtin_amdgcn_mfma_f32_16x16x32_bf16(al[mi], bh[ni], acc[mi][ni], 0, 0, 0);
                }

            if (step < 5) {
                int nb = buf ^ 1;
                stage(sh.g[nb][0], a0, a1, a2, a3);
                stage(sh.g[nb][2], b0, b1, b2, b3);
                __syncthreads();
                buf = nb;
            }
        }

        // epilogue: C/D layout col=lane&15, row=quad*4+reg (HW-verified)
        #pragma unroll
        for (int mi = 0; mi < 4; ++mi)
            #pragma unroll
            for (int ni = 0; ni < 4; ++ni) {
                int grow = M0 + wrow0 + mi * 16 + quad * 4;
                int gcol = nt * 128 + wcol0 + ni * 16 + lm;
                #pragma unroll
                for (int rr = 0; rr < 4; ++rr)
                    Cout[(size_t)(grow + rr) * TDN + gcol] = acc[mi][ni][rr];
            }
    }

    grid.sync();   // gemm partials + aggbuf zeros visible device-wide

    // ================= Phase 2: score + label reduce (all 256 blocks) ======
    {
        const int jc = bid & 15;         // j-chunk (96 wide)
        const int qt = (bid >> 4) & 1;   // q-tile (64)
        const int st = bid >> 5;         // s-tile (64)

        if (tid < 64) sh.s.lab[tid] = labels[st * 64 + tid];

        #pragma unroll
        for (int l = 0; l < 6; ++l) {
            int idx  = tid + l * 256;         // 0..1535
            int row  = idx / 24;              // 0..63
            int quad = idx - row * 24;        // 0..23
            int j    = jc * 96 + quad * 4;
            float4 hv = *(const float4*)&b1[j];
            float4 sv = make_float4(0.f, 0.f, 0.f, 0.f);
            #pragma unroll
            for (int p = 0; p < KSPLIT; ++p) {
                float4 h = *(const float4*)&hqp[(size_t)p * QN * TDN + (size_t)(qt * 64 + row) * TDN + j];
                float4 g = *(const float4*)&hsp[(size_t)p * SN * TDN + (size_t)(st * 64 + row) * TDN + j];
                hv.x += h.x; hv.y += h.y; hv.z += h.z; hv.w += h.w;
                sv.x += g.x; sv.y += g.y; sv.z += g.z; sv.w += g.w;
            }
            sh.s.hqT[quad*4+0][row] = hv.x; sh.s.hqT[quad*4+1][row] = hv.y;
            sh.s.hqT[quad*4+2][row] = hv.z; sh.s.hqT[quad*4+3][row] = hv.w;
            sh.s.hsT[quad*4+0][row] = sv.x; sh.s.hsT[quad*4+1][row] = sv.y;
            sh.s.hsT[quad*4+2][row] = sv.z; sh.s.hsT[quad*4+3][row] = sv.w;
        }
        if (tid < 24) {
            float4 wv = *(const float4*)&W2[jc * 96 + tid * 4];
            sh.s.w2s[tid*4+0] = wv.x; sh.s.w2s[tid*4+1] = wv.y;
            sh.s.w2s[tid*4+2] = wv.z; sh.s.w2s[tid*4+3] = wv.w;
        }
        __syncthreads();

        const int tx = tid & 15;
        const int ty = tid >> 4;
        float acc[4][4];
        #pragma unroll
        for (int i = 0; i < 4; ++i)
            #pragma unroll
            for (int j = 0; j < 4; ++j) acc[i][j] = 0.0f;

        #pragma unroll 4
        for (int jj = 0; jj < 96; ++jj) {
            float4 a4 = *(const float4*)&sh.s.hqT[jj][ty * 4];
            float4 b4 = *(const float4*)&sh.s.hsT[jj][tx * 4];
            float wv = sh.s.w2s[jj];
            float a[4] = {a4.x, a4.y, a4.z, a4.w};
            float b[4] = {b4.x, b4.y, b4.z, b4.w};
            #pragma unroll
            for (int i = 0; i < 4; ++i)
                #pragma unroll
                for (int j = 0; j < 4; ++j)
                    acc[i][j] += wv * fmaxf(a[i] + b[j], 0.0f);
        }

        #pragma unroll
        for (int i = 0; i < 4; ++i)
            *(float4*)&sh.s.sc[ty * 4 + i][tx * 4] =
                make_float4(acc[i][0], acc[i][1], acc[i][2], acc[i][3]);
        __syncthreads();

        {   // run-length label reduce: thread = (q-row, 16-wide s segment)
            int row = tid >> 2;
            int seg = tid & 3;
            float* aggrow = aggbuf + (size_t)(qt * 64 + row) * CN;
            int   runc = sh.s.lab[seg * 16];
            float runv = 0.0f;
            #pragma unroll
            for (int k = 0; k < 16; ++k) {
                int s = seg * 16 + k;
                int c = sh.s.lab[s];
                if (c != runc) { atomicAdd(&aggrow[runc], runv); runv = 0.0f; runc = c; }
                runv += sh.s.sc[row][s];
            }
            atomicAdd(&aggrow[runc], runv);
        }
    }

    grid.sync();   // aggbuf complete device-wide

    // ================= Phase 3: finale (block 0 only) ======================
    if (bid == 0) {
        if (tid < CN) sh.s.cnt[tid] = 0.0f;
        __syncthreads();
        atomicAdd(&sh.s.cnt[labels[tid]],       1.0f);
        atomicAdd(&sh.s.cnt[labels[tid + 256]], 1.0f);
        __syncthreads();

        float lossv = 0.0f;
        if (tid < QN) {
            const int q = tid;
            const float* rowp = aggbuf + (size_t)q * CN;
            float v[CN];
            #pragma unroll
            for (int c4 = 0; c4 < 16; ++c4) {
                float4 t4 = *(const float4*)&rowp[c4 * 4];
                v[c4*4+0] = t4.x; v[c4*4+1] = t4.y;
                v[c4*4+2] = t4.z; v[c4*4+3] = t4.w;
            }
            const int t = tgt[q];
            float vt = 0.0f;
            float best = -1e30f; int bi = 0;
            #pragma unroll
            for (int c = 0; c < CN; ++c) {
                v[c] /= fmaxf(sh.s.cnt[c], 1.0f);
                if (c == t) vt = v[c];
                if (v[c] > best) { best = v[c]; bi = c; }   // lower idx wins ties
            }
            float e = 0.0f;
            #pragma unroll
            for (int c = 0; c < CN; ++c)
                e += expf(v[c] - best);
            out[1 + q] = (bi == t) ? 1.0f : 0.0f;
            lossv = -(vt - best - logf(e));
        }
        #pragma unroll
        for (int off = 1; off < 64; off <<= 1)
            lossv += __shfl_xor(lossv, off);
        if ((tid & 63) == 0) sh.s.red[tid >> 6] = lossv;
        __syncthreads();
        if (tid == 0)
            out[0] = (sh.s.red[0] + sh.s.red[1]) / (float)QN;
    }
}

extern "C" void kernel_launch(void* const* d_in, const int* in_sizes, int n_in,
                              void* d_out, int out_size, void* d_ws, size_t ws_size,
                              hipStream_t stream) {
    const float* query   = (const float*)d_in[0];
    const float* support = (const float*)d_in[1];
    const float* W1      = (const float*)d_in[2];
    const float* b1      = (const float*)d_in[3];
    const float* W2      = (const float*)d_in[4];
    // d_in[5] = b2: uniform shift, cancels under log_softmax/argmax -> unused
    const int* labels = (const int*)d_in[6];
    const int* tgt    = (const int*)d_in[7];

    float* ws     = (float*)d_ws;
    float* hqp    = ws;                    // KSPLIT*QN*TDN
    float* hsp    = hqp + HQP_ELEMS;       // KSPLIT*SN*TDN
    float* aggbuf = hsp + HSP_ELEMS;       // QN*CN (zeroed in phase 1)
    float* out    = (float*)d_out;

    void* args[] = { (void*)&query, (void*)&support, (void*)&W1, (void*)&b1,
                     (void*)&W2, (void*)&labels, (void*)&tgt,
                     (void*)&hqp, (void*)&hsp, (void*)&aggbuf, (void*)&out };
    hipLaunchCooperativeKernel((const void*)mega_kernel,
                               dim3(256), dim3(256), args, 0, stream);
}

// Round 7
// 143.558 us; speedup vs baseline: 1.4119x; 1.4119x over previous
//
#include <hip/hip_runtime.h>
#include <math.h>

#define QN 128
#define SN 512
#define DN 768
#define TDN 1536
#define CN 64
#define KSPLIT 2
#define KCH 384   // 768 / KSPLIT

#define HQP_ELEMS (KSPLIT * QN * TDN)
#define HSP_ELEMS (KSPLIT * SN * TDN)
#define ZERO_ELEMS (QN * CN)

typedef short short8 __attribute__((ext_vector_type(8)));
typedef float f32x4 __attribute__((ext_vector_type(4)));

#define LDS_STRIDE 40            // 32 k + 8 pad (bf16) -> 16B-aligned rows
#define PLANE (128 * LDS_STRIDE) // shorts per plane

__device__ __forceinline__ short bf16_rtn(float x) {
    unsigned u = __float_as_uint(x);
    return (short)((u + 0x7fffu + ((u >> 16) & 1u)) >> 16);
}
__device__ __forceinline__ float bf16_tof(short s) {
    return __uint_as_float(((unsigned)(unsigned short)s) << 16);
}

// ---------------------------------------------------------------------------
// bf16x3 MFMA GEMM: out[m][n] = sum_k A[m][k]*W1[n][Koff+k], split-K 2.
// grid (12, 5, 2) = 120 blocks; block 256 = 4 waves, each a 64x64 quadrant
// of the 128x128 tile (4x4 subtiles of 16x16x32 MFMA, 3 MFMAs per pair for
// ~2^-18 relative error). (nt==0,kz==0) blocks also zero aggbuf + donecnt.
// ---------------------------------------------------------------------------
__global__ __launch_bounds__(256) void gemm_kernel(
    const float* __restrict__ query, const float* __restrict__ support,
    const float* __restrict__ W1, float* __restrict__ hqp, float* __restrict__ hsp,
    float* __restrict__ zbuf, int* __restrict__ donecnt)
{
    const int nt = blockIdx.x;   // 0..11
    const int mt = blockIdx.y;   // 0..4
    const int kz = blockIdx.z;   // 0..1
    const int tid = threadIdx.x;

    if (nt == 0 && kz == 0) {    // zero aggbuf (5 blocks x 256 thr x 8 floats)
        int o = (mt * 256 + tid) * 8;
        if (o < ZERO_ELEMS) {
            *(float4*)&zbuf[o]     = make_float4(0.f, 0.f, 0.f, 0.f);
            *(float4*)&zbuf[o + 4] = make_float4(0.f, 0.f, 0.f, 0.f);
        }
        if (mt == 0 && tid == 0) *donecnt = 0;
    }

    const float* A;
    float* Cout;
    int M0, Koff;
    if (mt == 0) { A = query;   M0 = 0;              Koff = 0;  Cout = hqp + (size_t)kz * QN * TDN; }
    else         { A = support; M0 = (mt - 1) * 128; Koff = DN; Cout = hsp + (size_t)kz * SN * TDN; }

    __shared__ short lds[2][4][PLANE];   // [buf][Ah, Al, Bh, Bl]

    const int r  = tid >> 1;         // staging row 0..127
    const int kh = (tid & 1) * 16;   // k-offset 0 or 16

    const float* Arow = &A [(size_t)(M0 + r) * DN  + kz * KCH + kh];
    const float* Brow = &W1[(size_t)(nt * 128 + r) * TDN + Koff + kz * KCH + kh];

    f32x4 acc[4][4];
    #pragma unroll
    for (int i = 0; i < 4; ++i)
        #pragma unroll
        for (int j = 0; j < 4; ++j)
            acc[i][j] = (f32x4){0.f, 0.f, 0.f, 0.f};

    auto stage = [&](short* plane, float4 v0, float4 v1, float4 v2, float4 v3) {
        float f[16] = {v0.x,v0.y,v0.z,v0.w, v1.x,v1.y,v1.z,v1.w,
                       v2.x,v2.y,v2.z,v2.w, v3.x,v3.y,v3.z,v3.w};
        short hi[16], lo[16];
        #pragma unroll
        for (int i = 0; i < 16; ++i) {
            hi[i] = bf16_rtn(f[i]);
            lo[i] = bf16_rtn(f[i] - bf16_tof(hi[i]));
        }
        short* dsth = plane + r * LDS_STRIDE + kh;
        #pragma unroll
        for (int i = 0; i < 16; ++i) dsth[i] = hi[i];
        short* dstl = plane + PLANE + r * LDS_STRIDE + kh;
        #pragma unroll
        for (int i = 0; i < 16; ++i) dstl[i] = lo[i];
    };

    {   // prologue: stage step 0 into buf 0
        float4 a0 = *(const float4*)(Arow),     a1 = *(const float4*)(Arow + 4);
        float4 a2 = *(const float4*)(Arow + 8), a3 = *(const float4*)(Arow + 12);
        float4 b0 = *(const float4*)(Brow),     b1 = *(const float4*)(Brow + 4);
        float4 b2 = *(const float4*)(Brow + 8), b3 = *(const float4*)(Brow + 12);
        stage(lds[0][0], a0, a1, a2, a3);
        stage(lds[0][2], b0, b1, b2, b3);
    }
    __syncthreads();

    const int lane  = tid & 63;
    const int w     = tid >> 6;
    const int lm    = lane & 15;
    const int quad  = lane >> 4;
    const int wrow0 = (w >> 1) * 64;
    const int wcol0 = (w & 1) * 64;

    int buf = 0;
    for (int step = 0; step < 12; ++step) {
        float4 a0, a1, a2, a3, b0, b1, b2, b3;
        if (step < 11) {
            const float* An = Arow + (step + 1) * 32;
            const float* Bn = Brow + (step + 1) * 32;
            a0 = *(const float4*)(An);     a1 = *(const float4*)(An + 4);
            a2 = *(const float4*)(An + 8); a3 = *(const float4*)(An + 12);
            b0 = *(const float4*)(Bn);     b1 = *(const float4*)(Bn + 4);
            b2 = *(const float4*)(Bn + 8); b3 = *(const float4*)(Bn + 12);
        }

        const short* Ah = lds[buf][0];
        const short* Al = lds[buf][1];
        const short* Bh = lds[buf][2];
        const short* Bl = lds[buf][3];

        short8 ah[4], al[4], bh[4], bl[4];
        #pragma unroll
        for (int mi = 0; mi < 4; ++mi) {
            int off = (wrow0 + mi * 16 + lm) * LDS_STRIDE + quad * 8;
            ah[mi] = *(const short8*)&Ah[off];
            al[mi] = *(const short8*)&Al[off];
        }
        #pragma unroll
        for (int ni = 0; ni < 4; ++ni) {
            int off = (wcol0 + ni * 16 + lm) * LDS_STRIDE + quad * 8;
            bh[ni] = *(const short8*)&Bh[off];
            bl[ni] = *(const short8*)&Bl[off];
        }
        #pragma unroll
        for (int mi = 0; mi < 4; ++mi)
            #pragma unroll
            for (int ni = 0; ni < 4; ++ni) {
                acc[mi][ni] = __builtin_amdgcn_mfma_f32_16x16x32_bf16(ah[mi], bh[ni], acc[mi][ni], 0, 0, 0);
                acc[mi][ni] = __builtin_amdgcn_mfma_f32_16x16x32_bf16(ah[mi], bl[ni], acc[mi][ni], 0, 0, 0);
                acc[mi][ni] = __builtin_amdgcn_mfma_f32_16x16x32_bf16(al[mi], bh[ni], acc[mi][ni], 0, 0, 0);
            }

        if (step < 11) {
            int nb = buf ^ 1;
            stage(lds[nb][0], a0, a1, a2, a3);
            stage(lds[nb][2], b0, b1, b2, b3);
            __syncthreads();
            buf = nb;
        }
    }

    // epilogue: C/D layout col=lane&15, row=quad*4+reg (HW-verified)
    #pragma unroll
    for (int mi = 0; mi < 4; ++mi)
        #pragma unroll
        for (int ni = 0; ni < 4; ++ni) {
            int grow = M0 + wrow0 + mi * 16 + quad * 4;
            int gcol = nt * 128 + wcol0 + ni * 16 + lm;
            #pragma unroll
            for (int rr = 0; rr < 4; ++rr)
                Cout[(size_t)(grow + rr) * TDN + gcol] = acc[mi][ni][rr];
        }
}

// ---------------------------------------------------------------------------
// Score + label reduce + last-block finale. grid (16, 2, 8) = 256 blocks.
// Each block: stage hq/hs transposed (2 split-K partials summed, b1 folded),
// 64x64 relu-dot tile (4x4 micro), LDS spill, run-length label reduce,
// device atomicAdd into aggbuf. Last block to finish (donecnt) runs the
// finale: counts, per-query mean/log_softmax/argmax/loss -> out.
// ---------------------------------------------------------------------------
__global__ __launch_bounds__(256) void score_kernel(
    const float* __restrict__ hqp, const float* __restrict__ hsp,
    const float* __restrict__ b1, const float* __restrict__ W2,
    const int* __restrict__ labels, const int* __restrict__ tgt,
    float* __restrict__ aggbuf, int* __restrict__ donecnt,
    float* __restrict__ out)
{
    const int jc = blockIdx.x;   // 0..15
    const int qt = blockIdx.y;   // 0..1
    const int st = blockIdx.z;   // 0..7

    __shared__ float hqT[96][64];
    __shared__ float hsT[96][64];
    __shared__ float w2s[96];
    __shared__ float sc[64][68];
    __shared__ int   lab[64];
    __shared__ float cnt[CN];
    __shared__ float red[2];
    __shared__ int   isLast;

    const int tid = threadIdx.x;
    if (tid < 64) lab[tid] = labels[st * 64 + tid];

    #pragma unroll
    for (int l = 0; l < 6; ++l) {
        int idx  = tid + l * 256;         // 0..1535
        int row  = idx / 24;              // 0..63
        int quad = idx - row * 24;        // 0..23
        int j    = jc * 96 + quad * 4;
        float4 hv = *(const float4*)&b1[j];
        float4 sv = make_float4(0.f, 0.f, 0.f, 0.f);
        #pragma unroll
        for (int p = 0; p < KSPLIT; ++p) {
            float4 h = *(const float4*)&hqp[(size_t)p * QN * TDN + (size_t)(qt * 64 + row) * TDN + j];
            float4 g = *(const float4*)&hsp[(size_t)p * SN * TDN + (size_t)(st * 64 + row) * TDN + j];
            hv.x += h.x; hv.y += h.y; hv.z += h.z; hv.w += h.w;
            sv.x += g.x; sv.y += g.y; sv.z += g.z; sv.w += g.w;
        }
        hqT[quad*4+0][row] = hv.x; hqT[quad*4+1][row] = hv.y;
        hqT[quad*4+2][row] = hv.z; hqT[quad*4+3][row] = hv.w;
        hsT[quad*4+0][row] = sv.x; hsT[quad*4+1][row] = sv.y;
        hsT[quad*4+2][row] = sv.z; hsT[quad*4+3][row] = sv.w;
    }
    if (tid < 24) {
        float4 wv = *(const float4*)&W2[jc * 96 + tid * 4];
        w2s[tid*4+0] = wv.x; w2s[tid*4+1] = wv.y;
        w2s[tid*4+2] = wv.z; w2s[tid*4+3] = wv.w;
    }
    __syncthreads();

    const int tx = tid & 15;
    const int ty = tid >> 4;
    float acc[4][4];
    #pragma unroll
    for (int i = 0; i < 4; ++i)
        #pragma unroll
        for (int j = 0; j < 4; ++j) acc[i][j] = 0.0f;

    #pragma unroll 4
    for (int jj = 0; jj < 96; ++jj) {
        float4 a4 = *(const float4*)&hqT[jj][ty * 4];
        float4 b4 = *(const float4*)&hsT[jj][tx * 4];
        float wv = w2s[jj];
        float a[4] = {a4.x, a4.y, a4.z, a4.w};
        float b[4] = {b4.x, b4.y, b4.z, b4.w};
        #pragma unroll
        for (int i = 0; i < 4; ++i)
            #pragma unroll
            for (int j = 0; j < 4; ++j)
                acc[i][j] += wv * fmaxf(a[i] + b[j], 0.0f);
    }

    #pragma unroll
    for (int i = 0; i < 4; ++i)
        *(float4*)&sc[ty * 4 + i][tx * 4] =
            make_float4(acc[i][0], acc[i][1], acc[i][2], acc[i][3]);
    __syncthreads();

    {   // run-length label reduce: thread = (q-row, 16-wide s segment)
        int row = tid >> 2;
        int seg = tid & 3;
        float* aggrow = aggbuf + (size_t)(qt * 64 + row) * CN;
        int   runc = lab[seg * 16];
        float runv = 0.0f;
        #pragma unroll
        for (int k = 0; k < 16; ++k) {
            int s = seg * 16 + k;
            int c = lab[s];
            if (c != runc) { atomicAdd(&aggrow[runc], runv); runv = 0.0f; runc = c; }
            runv += sc[row][s];
        }
        atomicAdd(&aggrow[runc], runv);
    }

    // -------- last-block-done finale --------
    __syncthreads();                 // barrier drains this block's atomics (vmcnt)
    if (tid == 0) {
        __threadfence();             // release: aggbuf adds before counter bump
        isLast = (atomicAdd(donecnt, 1) == 255);
    }
    __syncthreads();
    if (!isLast) return;
    __threadfence();                 // acquire: see all blocks' aggbuf adds

    if (tid < CN) cnt[tid] = 0.0f;
    __syncthreads();
    atomicAdd(&cnt[labels[tid]],       1.0f);
    atomicAdd(&cnt[labels[tid + 256]], 1.0f);
    __syncthreads();

    float lossv = 0.0f;
    if (tid < QN) {
        const int q = tid;
        const float* rowp = aggbuf + (size_t)q * CN;
        const int t = tgt[q];
        float best = -1e30f, vt = 0.0f;
        int bi = 0;
        #pragma unroll
        for (int c = 0; c < CN; ++c) {
            float v = __hip_atomic_load(&rowp[c], __ATOMIC_RELAXED,
                                        __HIP_MEMORY_SCOPE_AGENT)
                      / fmaxf(cnt[c], 1.0f);
            if (v > best) { best = v; bi = c; }   // lower idx wins ties
            if (c == t) vt = v;
        }
        float e = 0.0f;
        #pragma unroll
        for (int c = 0; c < CN; ++c) {
            float v = __hip_atomic_load(&rowp[c], __ATOMIC_RELAXED,
                                        __HIP_MEMORY_SCOPE_AGENT)
                      / fmaxf(cnt[c], 1.0f);
            e += expf(v - best);
        }
        out[1 + q] = (bi == t) ? 1.0f : 0.0f;
        lossv = -(vt - best - logf(e));
    }
    #pragma unroll
    for (int off = 1; off < 64; off <<= 1)
        lossv += __shfl_xor(lossv, off);
    if ((tid & 63) == 0) red[tid >> 6] = lossv;   // only groups 0,1 nonzero
    __syncthreads();
    if (tid == 0) out[0] = (red[0] + red[1]) / (float)QN;
}

extern "C" void kernel_launch(void* const* d_in, const int* in_sizes, int n_in,
                              void* d_out, int out_size, void* d_ws, size_t ws_size,
                              hipStream_t stream) {
    const float* query   = (const float*)d_in[0];
    const float* support = (const float*)d_in[1];
    const float* W1      = (const float*)d_in[2];
    const float* b1      = (const float*)d_in[3];
    const float* W2      = (const float*)d_in[4];
    // d_in[5] = b2: uniform shift, cancels under log_softmax/argmax -> unused
    const int* labels = (const int*)d_in[6];
    const int* tgt    = (const int*)d_in[7];

    float* ws      = (float*)d_ws;
    float* hqp     = ws;                   // KSPLIT*QN*TDN
    float* hsp     = hqp + HQP_ELEMS;      // KSPLIT*SN*TDN
    float* aggbuf  = hsp + HSP_ELEMS;      // QN*CN (zeroed by gemm)
    int*   donecnt = (int*)(aggbuf + QN * CN);
    float* out     = (float*)d_out;

    hipLaunchKernelGGL(gemm_kernel, dim3(12, 5, 2), dim3(256), 0, stream,
                       query, support, W1, hqp, hsp, aggbuf, donecnt);
    hipLaunchKernelGGL(score_kernel, dim3(16, 2, 8), dim3(256), 0, stream,
                       hqp, hsp, b1, W2, labels, tgt, aggbuf, donecnt, out);
}